// Round 4
// baseline (217.340 us; speedup 1.0000x reference)
//
#include <hip/hip_runtime.h>
#include <math.h>

#define B_    64
#define QLEN  32
#define DLEN  2048
#define WORD  300
#define ENT   128
#define AD    256
#define NK    11
#define KDIM  428
#define KHALF 224
#define KSH   7            // k-steps (of 32) per half

typedef __bf16 bf16x8 __attribute__((ext_vector_type(8)));
typedef __bf16 bf16x4 __attribute__((ext_vector_type(4)));
typedef float  f32x4  __attribute__((ext_vector_type(4)));

static __device__ const float d_mus[NK] =
    {-0.9f,-0.7f,-0.5f,-0.3f,-0.1f,0.1f,0.3f,0.5f,0.7f,0.9f,1.0f};
static __device__ const float d_coef[NK] =
    {-50.f,-50.f,-50.f,-50.f,-50.f,-50.f,-50.f,-50.f,-50.f,-50.f,-500000.f};

// ---------------------------------------------------------------------------
// W-pack: Wp bf16 in B-fragment order. tile(s,nb) = 64 lanes x 16B.
// lane l, j: B[k = s*32 + (l>>4)*8 + j][col = nb*16 + (l&15)]
// ---------------------------------------------------------------------------
__global__ __launch_bounds__(256) void knrm_wpack(
    const float* __restrict__ Wt, const float* __restrict__ We,
    const float* __restrict__ bt, const float* __restrict__ be,
    __bf16* __restrict__ Wp, float* __restrict__ bias)
{
    const int idx = blockIdx.x * 256 + threadIdx.x;   // 0..14335
    if (idx < AD) bias[idx] = bt[idx] + be[idx];
    const int tile = idx >> 6, l = idx & 63;
    const int s  = tile >> 4, nb = tile & 15;
    const int col = nb * 16 + (l & 15);
    const int k0  = s * 32 + (l >> 4) * 8;
    bf16x8 h;
    #pragma unroll
    for (int j = 0; j < 8; ++j) {
        const int k = k0 + j;
        float v = 0.f;
        if (k < WORD)      v = Wt[(size_t)k * AD + col];
        else if (k < KDIM) v = We[(size_t)(k - WORD) * AD + col];
        h[j] = (__bf16)v;
    }
    *(bf16x8*)((char*)Wp + (size_t)idx * 16) = h;
}

// ---------------------------------------------------------------------------
// Kernel Q: fp32 transform of query rows; writes qhat bf16, XOR-swizzled:
// byte = (q*512 + col*2) ^ ((q&7)<<4) within each batch slab of 16 KB.
// ---------------------------------------------------------------------------
#define XPAD 432
__global__ __launch_bounds__(256) void knrm_qtrans(
    const int* __restrict__ qtok,
    const float* __restrict__ qent,
    const float* __restrict__ emb,
    const float* __restrict__ Wt, const float* __restrict__ bt,
    const float* __restrict__ We, const float* __restrict__ be,
    char* __restrict__ qhatb)
{
    __shared__ float Xs[32 * XPAD];
    const int tid  = threadIdx.x;
    const int row0 = blockIdx.x * 32;

    for (int r = 0; r < 32; ++r) {
        const int row = row0 + r;
        const int tok = qtok[row] + 1;
        const float* __restrict__ er = emb + (size_t)tok * WORD;
        const float* __restrict__ xr = qent + (size_t)row * ENT;
        for (int c = tid; c < KDIM; c += 256)
            Xs[r * XPAD + c] = (c < WORD) ? er[c] : xr[c - WORD];
    }
    __syncthreads();

    const int rg   = tid >> 6;
    const int cg   = tid & 63;
    const int col0 = cg * 4;

    float acc[8][4];
    #pragma unroll
    for (int j = 0; j < 8; ++j)
        acc[j][0] = acc[j][1] = acc[j][2] = acc[j][3] = 0.f;

    for (int i = 0; i < KDIM; i += 4) {
        const float* __restrict__ Wbase =
            (i < WORD) ? (Wt + (size_t)i * AD) : (We + (size_t)(i - WORD) * AD);
        float4 xv[8];
        #pragma unroll
        for (int j = 0; j < 8; ++j)
            xv[j] = *(const float4*)(&Xs[(rg * 8 + j) * XPAD + i]);
        #pragma unroll
        for (int s = 0; s < 4; ++s) {
            const float4 w = *(const float4*)(Wbase + (size_t)s * AD + col0);
            #pragma unroll
            for (int j = 0; j < 8; ++j) {
                const float x = reinterpret_cast<const float*>(&xv[j])[s];
                acc[j][0] = fmaf(x, w.x, acc[j][0]);
                acc[j][1] = fmaf(x, w.y, acc[j][1]);
                acc[j][2] = fmaf(x, w.z, acc[j][2]);
                acc[j][3] = fmaf(x, w.w, acc[j][3]);
            }
        }
    }

    const float4 bt4 = *(const float4*)(bt + col0);
    const float4 be4 = *(const float4*)(be + col0);
    const float bias[4] = {bt4.x + be4.x, bt4.y + be4.y,
                           bt4.z + be4.z, bt4.w + be4.w};
    float ssq[8];
    #pragma unroll
    for (int j = 0; j < 8; ++j) {
        float s = 0.f;
        #pragma unroll
        for (int c = 0; c < 4; ++c) {
            const float v = fmaxf(acc[j][c] + bias[c], 0.f);
            acc[j][c] = v;
            s = fmaf(v, v, s);
        }
        ssq[j] = s;
    }
    #pragma unroll
    for (int m = 32; m; m >>= 1) {
        #pragma unroll
        for (int j = 0; j < 8; ++j)
            ssq[j] += __shfl_xor(ssq[j], m, 64);
    }
    char* qb = qhatb + (size_t)blockIdx.x * (QLEN * AD * 2);
    #pragma unroll
    for (int j = 0; j < 8; ++j) {
        const int q   = rg * 8 + j;
        const int row = row0 + q;
        const float rn = (qtok[row] == -1) ? 0.f
                                           : 1.f / (sqrtf(ssq[j]) + 1e-9f);
        bf16x4 h;
        #pragma unroll
        for (int c = 0; c < 4; ++c) h[c] = (__bf16)(acc[j][c] * rn);
        const int byte = (q * 512 + col0 * 2) ^ ((q & 7) << 4);
        *(bf16x4*)(qb + byte) = h;
    }
}

// ---------------------------------------------------------------------------
// Kernel D v4: 512 threads (8 waves), 64 docs/block, K-split X staging with
// T14 async prefetch of half 1; Q B-frags from global; swapped sims operands.
// No min-wave launch bound (v3's (512,6) caused scratch spill: WRITE 93 MB).
// ---------------------------------------------------------------------------
__global__ __launch_bounds__(512) void knrm_doc(
    const int* __restrict__ dtok,
    const float* __restrict__ dent,
    const float* __restrict__ emb,
    const __bf16* __restrict__ Wp,
    const float* __restrict__ bias,
    const char* __restrict__ qhatb,
    float* __restrict__ ksum,    // [B, NK, QLEN]
    float* __restrict__ simsum)  // [B, QLEN]
{
    __shared__ __align__(16) char sm[32768 + 2048];
    char*  Xb   = sm;                      // X half [64][224] bf16 swz; later T [64][256] bf16 swz
    float* red  = (float*)(sm + 32768);    // [12][32]
    float* ssq  = red + 384;               // [64]
    int*   toks = (int*)(ssq + 64);        // [64] tok+1

    const int tid = threadIdx.x;
    const int b   = blockIdx.y;
    const int d0  = blockIdx.x * 64;
    const int w   = tid >> 6;
    const int l   = tid & 63;
    const int lr  = l & 15;
    const int lg  = l >> 4;
    const int drow0 = b * DLEN + d0;

    for (int i = tid; i < 448; i += 512) red[i] = 0.f;
    if (tid < 64) toks[tid] = dtok[drow0 + tid] + 1;
    __syncthreads();

    // ---- stage half 0 (k 0..223 — pure emb gather), swizzled bf16 ----
    #pragma unroll
    for (int j = 0; j < 7; ++j) {
        const int i = tid + j * 512;           // 0..3583
        const int r = i / 56, s = i - r * 56;
        const f32x4 v = *(const f32x4*)(emb + (size_t)toks[r] * WORD + s * 4);
        bf16x4 hv;
        #pragma unroll
        for (int c = 0; c < 4; ++c) hv[c] = (__bf16)v[c];
        const int byte = (r * 448 + s * 8) ^ ((r & 7) << 4);
        *(bf16x4*)(Xb + byte) = hv;
    }
    __syncthreads();

    // ---- issue half-1 prefetch (k 224..427 + pad) into registers ----
    f32x4 pf[7];
    #pragma unroll
    for (int j = 0; j < 7; ++j) {
        const int i = tid + j * 512;
        const int r = i / 56, s = i - r * 56;
        const int k = KHALF + s * 4;
        if (k < WORD)
            pf[j] = *(const f32x4*)(emb + (size_t)toks[r] * WORD + k);
        else if (k < KDIM)
            pf[j] = *(const f32x4*)(dent + (size_t)(drow0 + r) * ENT + (k - WORD));
        else
            pf[j] = (f32x4){0.f, 0.f, 0.f, 0.f};
    }

    f32x4 acc[4][2];
    #pragma unroll
    for (int mf = 0; mf < 4; ++mf)
        #pragma unroll
        for (int nf = 0; nf < 2; ++nf)
            acc[mf][nf] = (f32x4){0.f, 0.f, 0.f, 0.f};

    // ---- MFMA half 0 ----
    #pragma unroll
    for (int s = 0; s < KSH; ++s) {
        bf16x8 a[4];
        #pragma unroll
        for (int mf = 0; mf < 4; ++mf) {
            const int row  = mf * 16 + lr;
            const int byte = (row * 448 + s * 64 + lg * 16) ^ ((row & 7) << 4);
            a[mf] = *(const bf16x8*)(Xb + byte);
        }
        bf16x8 bfv[2];
        #pragma unroll
        for (int nf = 0; nf < 2; ++nf) {
            const int tile = s * 16 + (w * 2 + nf);
            bfv[nf] = *(const bf16x8*)((const char*)Wp + (size_t)tile * 1024 + l * 16);
        }
        #pragma unroll
        for (int mf = 0; mf < 4; ++mf)
            #pragma unroll
            for (int nf = 0; nf < 2; ++nf)
                acc[mf][nf] = __builtin_amdgcn_mfma_f32_16x16x32_bf16(
                    a[mf], bfv[nf], acc[mf][nf], 0, 0, 0);
    }
    __syncthreads();   // half-0 reads done

    // ---- write half 1 from prefetch regs ----
    #pragma unroll
    for (int j = 0; j < 7; ++j) {
        const int i = tid + j * 512;
        const int r = i / 56, s = i - r * 56;
        bf16x4 hv;
        #pragma unroll
        for (int c = 0; c < 4; ++c) hv[c] = (__bf16)pf[j][c];
        const int byte = (r * 448 + s * 8) ^ ((r & 7) << 4);
        *(bf16x4*)(Xb + byte) = hv;
    }
    __syncthreads();

    // ---- MFMA half 1 ----
    #pragma unroll
    for (int s = 0; s < KSH; ++s) {
        bf16x8 a[4];
        #pragma unroll
        for (int mf = 0; mf < 4; ++mf) {
            const int row  = mf * 16 + lr;
            const int byte = (row * 448 + s * 64 + lg * 16) ^ ((row & 7) << 4);
            a[mf] = *(const bf16x8*)(Xb + byte);
        }
        bf16x8 bfv[2];
        #pragma unroll
        for (int nf = 0; nf < 2; ++nf) {
            const int tile = (KSH + s) * 16 + (w * 2 + nf);
            bfv[nf] = *(const bf16x8*)((const char*)Wp + (size_t)tile * 1024 + l * 16);
        }
        #pragma unroll
        for (int mf = 0; mf < 4; ++mf)
            #pragma unroll
            for (int nf = 0; nf < 2; ++nf)
                acc[mf][nf] = __builtin_amdgcn_mfma_f32_16x16x32_bf16(
                    a[mf], bfv[nf], acc[mf][nf], 0, 0, 0);
    }
    __syncthreads();   // all X reads done; Xb reusable as T

    // bias + relu + row square-sums (wave's 32-col slice)
    float bv[2];
    #pragma unroll
    for (int nf = 0; nf < 2; ++nf) bv[nf] = bias[w * 32 + nf * 16 + lr];
    float sq[4][4];
    #pragma unroll
    for (int mf = 0; mf < 4; ++mf)
        #pragma unroll
        for (int reg = 0; reg < 4; ++reg) {
            const float v0 = fmaxf(acc[mf][0][reg] + bv[0], 0.f);
            const float v1 = fmaxf(acc[mf][1][reg] + bv[1], 0.f);
            acc[mf][0][reg] = v0;
            acc[mf][1][reg] = v1;
            sq[mf][reg] = fmaf(v0, v0, v1 * v1);
        }
    #pragma unroll
    for (int m = 1; m <= 8; m <<= 1)
        #pragma unroll
        for (int mf = 0; mf < 4; ++mf)
            #pragma unroll
            for (int reg = 0; reg < 4; ++reg)
                sq[mf][reg] += __shfl_xor(sq[mf][reg], m, 64);
    if (lr == 0) {
        #pragma unroll
        for (int mf = 0; mf < 4; ++mf)
            #pragma unroll
            for (int reg = 0; reg < 4; ++reg)
                atomicAdd(&ssq[mf * 16 + lg * 4 + reg], sq[mf][reg]);
    }
    // write T [doc][256] bf16, byte = (doc*512+col*2)^((doc&7)<<4)
    #pragma unroll
    for (int mf = 0; mf < 4; ++mf)
        #pragma unroll
        for (int nf = 0; nf < 2; ++nf)
            #pragma unroll
            for (int reg = 0; reg < 4; ++reg) {
                const int doc  = mf * 16 + lg * 4 + reg;
                const int col  = w * 32 + nf * 16 + lr;
                const int byte = (doc * 512 + col * 2) ^ ((doc & 7) << 4);
                *(__bf16*)(Xb + byte) = (__bf16)acc[mf][nf][reg];
            }
    __syncthreads();   // T + ssq visible

    // ---- sims: wave w -> dtile = w&3 (16 docs as M), qtile = w>>2 (16 q as N)
    const int dtile = w & 3, qtile = w >> 2;
    const int tdoc  = dtile * 16 + lr;
    const int q     = qtile * 16 + lr;
    const char* __restrict__ qb = qhatb + (size_t)b * (QLEN * AD * 2);
    f32x4 sacc = (f32x4){0.f, 0.f, 0.f, 0.f};
    #pragma unroll
    for (int s = 0; s < 8; ++s) {
        const int tbyte = (tdoc * 512 + s * 64 + lg * 16) ^ ((tdoc & 7) << 4);
        const bf16x8 ta = *(const bf16x8*)(Xb + tbyte);
        const int qbyte = (q * 512 + s * 64 + lg * 16) ^ ((q & 7) << 4);
        const bf16x8 qv = *(const bf16x8*)(qb + qbyte);
        sacc = __builtin_amdgcn_mfma_f32_16x16x32_bf16(ta, qv, sacc, 0, 0, 0);
    }

    // ---- RBF: lane holds 4 docs (regs) x 1 q; accumulate in-lane over docs
    float kq[12];
    #pragma unroll
    for (int k = 0; k < 12; ++k) kq[k] = 0.f;
    #pragma unroll
    for (int reg = 0; reg < 4; ++reg) {
        const int doc = dtile * 16 + lg * 4 + reg;
        const float dnv = (toks[doc] == 0) ? 0.f
                                           : 1.f / (sqrtf(ssq[doc]) + 1e-9f);
        const float sv = sacc[reg] * dnv;
        kq[11] += sv;
        #pragma unroll
        for (int k = 0; k < NK; ++k) {
            const float t = sv - d_mus[k];
            kq[k] += __expf(d_coef[k] * t * t);
        }
    }
    #pragma unroll
    for (int m = 16; m <= 32; m <<= 1)
        #pragma unroll
        for (int k = 0; k < 12; ++k)
            kq[k] += __shfl_xor(kq[k], m, 64);
    if (lg == 0) {
        #pragma unroll
        for (int k = 0; k < 12; ++k)
            atomicAdd(&red[k * 32 + q], kq[k]);
    }
    __syncthreads();

    for (int i = tid; i < 384; i += 512) {
        const int k = i >> 5, qq = i & 31;
        if (k < NK) atomicAdd(&ksum[((size_t)b * NK + k) * QLEN + qq], red[i]);
        else        atomicAdd(&simsum[b * QLEN + qq], red[i]);
    }
}

// ---------------------------------------------------------------------------
__global__ __launch_bounds__(384) void knrm_final(
    const float* __restrict__ ksum,
    const float* __restrict__ simsum,
    const float* __restrict__ Wc, const float* __restrict__ bc,
    float* __restrict__ out)
{
    __shared__ float redq[NK][QLEN];
    __shared__ float res[NK];
    const int b = blockIdx.x;
    const int t = threadIdx.x;
    if (t < NK * QLEN) {
        const int k = t >> 5;
        const int q = t & 31;
        const float ms = simsum[b * QLEN + q];
        redq[k][q] = (ms != 0.0f)
            ? logf(ksum[((size_t)b * NK + k) * QLEN + q] + 1e-6f)
            : 0.0f;
    }
    __syncthreads();
    if (t < NK) {
        float s = 0.f;
        for (int q = 0; q < QLEN; ++q) s += redq[t][q];
        res[t] = s;
    }
    __syncthreads();
    if (t == 0) {
        float s = bc[0];
        for (int k = 0; k < NK; ++k) s += res[k] * Wc[k];
        out[b] = s;
    }
}

// ---------------------------------------------------------------------------
extern "C" void kernel_launch(void* const* d_in, const int* in_sizes, int n_in,
                              void* d_out, int out_size, void* d_ws, size_t ws_size,
                              hipStream_t stream)
{
    (void)in_sizes; (void)n_in; (void)out_size; (void)ws_size;
    const int*   qtok = (const int*)d_in[0];
    const int*   dtok = (const int*)d_in[1];
    const float* qent = (const float*)d_in[2];
    const float* dent = (const float*)d_in[3];
    const float* emb  = (const float*)d_in[4];
    const float* Wt   = (const float*)d_in[5];
    const float* bt   = (const float*)d_in[6];
    const float* We   = (const float*)d_in[7];
    const float* be   = (const float*)d_in[8];
    const float* Wc   = (const float*)d_in[9];
    const float* bc   = (const float*)d_in[10];
    float* out = (float*)d_out;

    char* ws = (char*)d_ws;
    char*   qhatb = ws;                                   // 1 MB bf16 swz
    __bf16* Wp    = (__bf16*)(ws + 1048576);              // 229376 B
    float*  bias  = (float*)(ws + 1048576 + 229376);      // 1 KB
    float*  ksum  = (float*)(ws + 1048576 + 229376 + 1024);        // 90112 B
    float*  simsum= (float*)(ws + 1048576 + 229376 + 1024 + 90112);// 8192 B

    hipMemsetAsync(ksum, 0, (size_t)(90112 + 8192), stream);

    knrm_wpack<<<dim3(56), dim3(256), 0, stream>>>(Wt, We, bt, be, Wp, bias);
    knrm_qtrans<<<dim3(B_), dim3(256), 0, stream>>>(
        qtok, qent, emb, Wt, bt, We, be, qhatb);
    knrm_doc<<<dim3(DLEN / 64, B_), dim3(512), 0, stream>>>(
        dtok, dent, emb, Wp, bias, qhatb, ksum, simsum);
    knrm_final<<<dim3(B_), dim3(384), 0, stream>>>(ksum, simsum, Wc, bc, out);
}

// Round 5
// 138.496 us; speedup vs baseline: 1.5693x; 1.5693x over previous
//
#include <hip/hip_runtime.h>
#include <math.h>

#define B_    64
#define QLEN  32
#define DLEN  2048
#define WORD  300
#define ENT   128
#define AD    256
#define NK    11
#define KDIM  428
#define NT32  14           // K-steps of 32 (448 padded)
#define BM    128          // docs per block (fused kernel)

typedef __bf16 bf16x8 __attribute__((ext_vector_type(8)));
typedef __bf16 bf16x4 __attribute__((ext_vector_type(4)));
typedef float  f32x4  __attribute__((ext_vector_type(4)));

static __device__ const float d_mus[NK] =
    {-0.9f,-0.7f,-0.5f,-0.3f,-0.1f,0.1f,0.3f,0.5f,0.7f,0.9f,1.0f};
static __device__ const float d_coef[NK] =
    {-50.f,-50.f,-50.f,-50.f,-50.f,-50.f,-50.f,-50.f,-50.f,-50.f,-500000.f};

// ---------------------------------------------------------------------------
// W-pack: Wp bf16 in B-fragment order. tile(s,nb) = 64 lanes x 16B.
// lane l, j: B[k = s*32 + (l>>4)*8 + j][col = nb*16 + (l&15)]
// ---------------------------------------------------------------------------
__global__ __launch_bounds__(256) void knrm_wpack(
    const float* __restrict__ Wt, const float* __restrict__ We,
    const float* __restrict__ bt, const float* __restrict__ be,
    __bf16* __restrict__ Wp, float* __restrict__ bias)
{
    const int idx = blockIdx.x * 256 + threadIdx.x;   // 0..14335
    if (idx < AD) bias[idx] = bt[idx] + be[idx];
    const int tile = idx >> 6, l = idx & 63;
    const int s  = tile >> 4, nb = tile & 15;
    const int col = nb * 16 + (l & 15);
    const int k0  = s * 32 + (l >> 4) * 8;
    bf16x8 h;
    #pragma unroll
    for (int j = 0; j < 8; ++j) {
        const int k = k0 + j;
        float v = 0.f;
        if (k < WORD)      v = Wt[(size_t)k * AD + col];
        else if (k < KDIM) v = We[(size_t)(k - WORD) * AD + col];
        h[j] = (__bf16)v;
    }
    *(bf16x8*)((char*)Wp + (size_t)idx * 16) = h;
}

// ---------------------------------------------------------------------------
// Kernel Q: fp32 transform of 8 query rows/block (256 blocks for CU coverage);
// writes qhat bf16, XOR-swizzled per 32-row batch slab of 16 KB:
// byte = (q*512 + col*2) ^ ((q&7)<<4).
// ---------------------------------------------------------------------------
__global__ __launch_bounds__(256) void knrm_qtrans(
    const int* __restrict__ qtok,
    const float* __restrict__ qent,
    const float* __restrict__ emb,
    const float* __restrict__ Wt, const float* __restrict__ bt,
    const float* __restrict__ We, const float* __restrict__ be,
    char* __restrict__ qhatb)
{
    __shared__ float Xs[8 * 432];
    const int tid  = threadIdx.x;
    const int row0 = blockIdx.x * 8;

    for (int r = 0; r < 8; ++r) {
        const int row = row0 + r;
        const int tok = qtok[row] + 1;
        const float* __restrict__ er = emb + (size_t)tok * WORD;
        const float* __restrict__ xr = qent + (size_t)row * ENT;
        for (int c = tid; c < KDIM; c += 256)
            Xs[r * 432 + c] = (c < WORD) ? er[c] : xr[c - WORD];
    }
    __syncthreads();

    const int rg   = tid >> 6;      // wave: rows rg*2, rg*2+1
    const int cg   = tid & 63;
    const int col0 = cg * 4;

    float acc[2][4];
    #pragma unroll
    for (int j = 0; j < 2; ++j)
        acc[j][0] = acc[j][1] = acc[j][2] = acc[j][3] = 0.f;

    for (int i = 0; i < KDIM; i += 4) {
        const float* __restrict__ Wbase =
            (i < WORD) ? (Wt + (size_t)i * AD) : (We + (size_t)(i - WORD) * AD);
        float4 xv[2];
        #pragma unroll
        for (int j = 0; j < 2; ++j)
            xv[j] = *(const float4*)(&Xs[(rg * 2 + j) * 432 + i]);
        #pragma unroll
        for (int s = 0; s < 4; ++s) {
            const float4 w = *(const float4*)(Wbase + (size_t)s * AD + col0);
            #pragma unroll
            for (int j = 0; j < 2; ++j) {
                const float x = reinterpret_cast<const float*>(&xv[j])[s];
                acc[j][0] = fmaf(x, w.x, acc[j][0]);
                acc[j][1] = fmaf(x, w.y, acc[j][1]);
                acc[j][2] = fmaf(x, w.z, acc[j][2]);
                acc[j][3] = fmaf(x, w.w, acc[j][3]);
            }
        }
    }

    const float4 bt4 = *(const float4*)(bt + col0);
    const float4 be4 = *(const float4*)(be + col0);
    const float bias[4] = {bt4.x + be4.x, bt4.y + be4.y,
                           bt4.z + be4.z, bt4.w + be4.w};
    float ssq[2];
    #pragma unroll
    for (int j = 0; j < 2; ++j) {
        float s = 0.f;
        #pragma unroll
        for (int c = 0; c < 4; ++c) {
            const float v = fmaxf(acc[j][c] + bias[c], 0.f);
            acc[j][c] = v;
            s = fmaf(v, v, s);
        }
        ssq[j] = s;
    }
    #pragma unroll
    for (int m = 32; m; m >>= 1) {
        #pragma unroll
        for (int j = 0; j < 2; ++j)
            ssq[j] += __shfl_xor(ssq[j], m, 64);
    }
    char* qb = qhatb + (size_t)(blockIdx.x >> 2) * (QLEN * AD * 2);
    #pragma unroll
    for (int j = 0; j < 2; ++j) {
        const int q   = (blockIdx.x & 3) * 8 + rg * 2 + j;   // q within batch
        const int row = row0 + rg * 2 + j;
        const float rn = (qtok[row] == -1) ? 0.f
                                           : 1.f / (sqrtf(ssq[j]) + 1e-9f);
        bf16x4 h;
        #pragma unroll
        for (int c = 0; c < 4; ++c) h[c] = (__bf16)(acc[j][c] * rn);
        const int byte = (q * 512 + col0 * 2) ^ ((q & 7) << 4);
        *(bf16x4*)(qb + byte) = h;
    }
}

// ---------------------------------------------------------------------------
// Fused kernel v5: 128 docs/block, 512 threads (8 waves, 2M x 4N, wave tile
// 64x64). K pipelined in 32-steps with ping-pong LDS (2x8KB) + issue-early
// register prefetch; one barrier per step. T (128x256 bf16, 64KB) overlays
// staging. Sims: 16 docs/wave x 32 q, T from LDS, qhat from L2.
// ---------------------------------------------------------------------------
__global__ __launch_bounds__(512) void knrm_fused(
    const int* __restrict__ dtok,
    const float* __restrict__ dent,
    const float* __restrict__ emb,
    const __bf16* __restrict__ Wp,
    const float* __restrict__ bias,
    const char* __restrict__ qhatb,
    float* __restrict__ ksum,    // [B, NK, QLEN]
    float* __restrict__ simsum)  // [B, QLEN]
{
    __shared__ __align__(16) char sm[65536 + 2048 + 512];
    float* red  = (float*)(sm + 65536);          // [12][32]
    float* ssq  = (float*)(sm + 65536 + 1536);   // [128]
    int*   toks = (int*)(sm + 65536 + 2048);     // [128] tok+1

    const int tid = threadIdx.x;
    const int b   = blockIdx.y;
    const int d0  = blockIdx.x * BM;
    const int drow0 = b * DLEN + d0;
    const int w  = tid >> 6;
    const int l  = tid & 63;
    const int lr = l & 15;
    const int lg = l >> 4;
    const int wM = w >> 2;       // 0..1 : doc half
    const int wN = w & 3;        // 0..3 : col quarter

    // zero red+ssq (contiguous 512 floats), load toks
    ((float*)(sm + 65536))[tid & 511] = 0.f;
    if (tid < BM) toks[tid] = dtok[drow0 + tid] + 1;
    __syncthreads();

    // gather one f32x4 of the X tile for K-step t, slot j (j=0,1)
    auto gather = [&](int t, int j) -> f32x4 {
        const int idx = tid + j * 512;           // 0..1023
        const int r   = idx >> 3;                // doc row 0..127
        const int k   = t * 32 + (idx & 7) * 4;  // col
        if (k < WORD)
            return *(const f32x4*)(emb + (size_t)toks[r] * WORD + k);
        if (k < KDIM)
            return *(const f32x4*)(dent + (size_t)(drow0 + r) * ENT + (k - WORD));
        return (f32x4){0.f, 0.f, 0.f, 0.f};
    };
    auto stash = [&](int buf, int j, f32x4 v) {
        const int idx = tid + j * 512;
        const int r   = idx >> 3;
        const int cb  = (idx & 7) * 8;           // byte of 4 bf16
        bf16x4 h;
        #pragma unroll
        for (int c = 0; c < 4; ++c) h[c] = (__bf16)v[c];
        *(bf16x4*)(sm + buf + ((r * 64 + cb) ^ ((r & 7) << 4))) = h;
    };

    f32x4 acc[4][4];
    #pragma unroll
    for (int mf = 0; mf < 4; ++mf)
        #pragma unroll
        for (int nf = 0; nf < 4; ++nf)
            acc[mf][nf] = (f32x4){0.f, 0.f, 0.f, 0.f};

    // prologue: stage step 0
    {
        const f32x4 v0 = gather(0, 0);
        const f32x4 v1 = gather(0, 1);
        stash(0, 0, v0);
        stash(0, 1, v1);
    }
    __syncthreads();

    int cur = 0;
    for (int t = 0; t < NT32; ++t) {
        f32x4 p0, p1;
        if (t + 1 < NT32) {                      // issue-early prefetch
            p0 = gather(t + 1, 0);
            p1 = gather(t + 1, 1);
        }
        bf16x8 a[4];
        #pragma unroll
        for (int mf = 0; mf < 4; ++mf) {
            const int row = wM * 64 + mf * 16 + lr;
            a[mf] = *(const bf16x8*)(sm + cur +
                        ((row * 64 + lg * 16) ^ ((row & 7) << 4)));
        }
        bf16x8 wv[4];
        #pragma unroll
        for (int nf = 0; nf < 4; ++nf) {
            const int tile = t * 16 + wN * 4 + nf;
            wv[nf] = *(const bf16x8*)((const char*)Wp + (size_t)tile * 1024 + l * 16);
        }
        #pragma unroll
        for (int mf = 0; mf < 4; ++mf)
            #pragma unroll
            for (int nf = 0; nf < 4; ++nf)
                acc[mf][nf] = __builtin_amdgcn_mfma_f32_16x16x32_bf16(
                    a[mf], wv[nf], acc[mf][nf], 0, 0, 0);
        if (t + 1 < NT32) {                      // write-late into other buffer
            stash(cur ^ 8192, 0, p0);
            stash(cur ^ 8192, 1, p1);
        }
        __syncthreads();
        cur ^= 8192;
    }

    // bias + relu + row square-sums
    float bv[4];
    #pragma unroll
    for (int nf = 0; nf < 4; ++nf) bv[nf] = bias[wN * 64 + nf * 16 + lr];
    float sq[4][4];
    #pragma unroll
    for (int mf = 0; mf < 4; ++mf)
        #pragma unroll
        for (int reg = 0; reg < 4; ++reg) {
            float s = 0.f;
            #pragma unroll
            for (int nf = 0; nf < 4; ++nf) {
                const float v = fmaxf(acc[mf][nf][reg] + bv[nf], 0.f);
                acc[mf][nf][reg] = v;
                s = fmaf(v, v, s);
            }
            sq[mf][reg] = s;
        }
    #pragma unroll
    for (int m = 1; m <= 8; m <<= 1)
        #pragma unroll
        for (int mf = 0; mf < 4; ++mf)
            #pragma unroll
            for (int reg = 0; reg < 4; ++reg)
                sq[mf][reg] += __shfl_xor(sq[mf][reg], m, 64);
    if (lr == 0) {
        #pragma unroll
        for (int mf = 0; mf < 4; ++mf)
            #pragma unroll
            for (int reg = 0; reg < 4; ++reg)
                atomicAdd(&ssq[wM * 64 + mf * 16 + lg * 4 + reg], sq[mf][reg]);
    }
    // write T [doc][256] bf16 over staging region
    #pragma unroll
    for (int mf = 0; mf < 4; ++mf)
        #pragma unroll
        for (int nf = 0; nf < 4; ++nf)
            #pragma unroll
            for (int reg = 0; reg < 4; ++reg) {
                const int doc  = wM * 64 + mf * 16 + lg * 4 + reg;
                const int col  = wN * 64 + nf * 16 + lr;
                const int byte = (doc * 512 + col * 2) ^ ((doc & 7) << 4);
                *(__bf16*)(sm + byte) = (__bf16)acc[mf][nf][reg];
            }
    __syncthreads();

    // ---- sims: wave w owns docs w*16..w*16+15 (M), all 32 q (2 N-frags)
    const int tdoc = w * 16 + lr;
    const char* __restrict__ qb = qhatb + (size_t)b * (QLEN * AD * 2);
    f32x4 s0 = (f32x4){0.f, 0.f, 0.f, 0.f};
    f32x4 s1 = (f32x4){0.f, 0.f, 0.f, 0.f};
    #pragma unroll
    for (int s = 0; s < 8; ++s) {
        const bf16x8 ta = *(const bf16x8*)(sm +
            ((tdoc * 512 + s * 64 + lg * 16) ^ ((tdoc & 7) << 4)));
        const bf16x8 q0 = *(const bf16x8*)(qb +
            ((lr * 512 + s * 64 + lg * 16) ^ ((lr & 7) << 4)));
        const bf16x8 q1 = *(const bf16x8*)(qb +
            (((lr + 16) * 512 + s * 64 + lg * 16) ^ (((lr + 16) & 7) << 4)));
        s0 = __builtin_amdgcn_mfma_f32_16x16x32_bf16(ta, q0, s0, 0, 0, 0);
        s1 = __builtin_amdgcn_mfma_f32_16x16x32_bf16(ta, q1, s1, 0, 0, 0);
    }

    // ---- RBF: lane holds 4 docs (regs) x q = lr (s0) and lr+16 (s1)
    float kq0[12], kq1[12];
    #pragma unroll
    for (int k = 0; k < 12; ++k) { kq0[k] = 0.f; kq1[k] = 0.f; }
    #pragma unroll
    for (int reg = 0; reg < 4; ++reg) {
        const int doc = w * 16 + lg * 4 + reg;
        const float dnv = (toks[doc] == 0) ? 0.f
                                           : 1.f / (sqrtf(ssq[doc]) + 1e-9f);
        const float sv0 = s0[reg] * dnv;
        const float sv1 = s1[reg] * dnv;
        kq0[11] += sv0;
        kq1[11] += sv1;
        #pragma unroll
        for (int k = 0; k < NK; ++k) {
            const float t0 = sv0 - d_mus[k];
            const float t1 = sv1 - d_mus[k];
            kq0[k] += __expf(d_coef[k] * t0 * t0);
            kq1[k] += __expf(d_coef[k] * t1 * t1);
        }
    }
    #pragma unroll
    for (int m = 16; m <= 32; m <<= 1)
        #pragma unroll
        for (int k = 0; k < 12; ++k) {
            kq0[k] += __shfl_xor(kq0[k], m, 64);
            kq1[k] += __shfl_xor(kq1[k], m, 64);
        }
    if (lg == 0) {
        #pragma unroll
        for (int k = 0; k < 12; ++k) {
            atomicAdd(&red[k * 32 + lr], kq0[k]);
            atomicAdd(&red[k * 32 + 16 + lr], kq1[k]);
        }
    }
    __syncthreads();

    for (int i = tid; i < 384; i += 512) {
        const int k = i >> 5, qq = i & 31;
        if (k < NK) atomicAdd(&ksum[((size_t)b * NK + k) * QLEN + qq], red[i]);
        else        atomicAdd(&simsum[b * QLEN + qq], red[i]);
    }
}

// ---------------------------------------------------------------------------
__global__ __launch_bounds__(384) void knrm_final(
    const float* __restrict__ ksum,
    const float* __restrict__ simsum,
    const float* __restrict__ Wc, const float* __restrict__ bc,
    float* __restrict__ out)
{
    __shared__ float redq[NK][QLEN];
    __shared__ float res[NK];
    const int b = blockIdx.x;
    const int t = threadIdx.x;
    if (t < NK * QLEN) {
        const int k = t >> 5;
        const int q = t & 31;
        const float ms = simsum[b * QLEN + q];
        redq[k][q] = (ms != 0.0f)
            ? logf(ksum[((size_t)b * NK + k) * QLEN + q] + 1e-6f)
            : 0.0f;
    }
    __syncthreads();
    if (t < NK) {
        float s = 0.f;
        for (int q = 0; q < QLEN; ++q) s += redq[t][q];
        res[t] = s;
    }
    __syncthreads();
    if (t == 0) {
        float s = bc[0];
        for (int k = 0; k < NK; ++k) s += res[k] * Wc[k];
        out[b] = s;
    }
}

// ---------------------------------------------------------------------------
extern "C" void kernel_launch(void* const* d_in, const int* in_sizes, int n_in,
                              void* d_out, int out_size, void* d_ws, size_t ws_size,
                              hipStream_t stream)
{
    (void)in_sizes; (void)n_in; (void)out_size; (void)ws_size;
    const int*   qtok = (const int*)d_in[0];
    const int*   dtok = (const int*)d_in[1];
    const float* qent = (const float*)d_in[2];
    const float* dent = (const float*)d_in[3];
    const float* emb  = (const float*)d_in[4];
    const float* Wt   = (const float*)d_in[5];
    const float* bt   = (const float*)d_in[6];
    const float* We   = (const float*)d_in[7];
    const float* be   = (const float*)d_in[8];
    const float* Wc   = (const float*)d_in[9];
    const float* bc   = (const float*)d_in[10];
    float* out = (float*)d_out;

    char* ws = (char*)d_ws;
    char*   qhatb = ws;                                   // 1 MB bf16 swz
    __bf16* Wp    = (__bf16*)(ws + 1048576);              // 229376 B
    float*  bias  = (float*)(ws + 1048576 + 229376);      // 1 KB
    float*  ksum  = (float*)(ws + 1048576 + 229376 + 1024);        // 90112 B
    float*  simsum= (float*)(ws + 1048576 + 229376 + 1024 + 90112);// 8192 B

    hipMemsetAsync(ksum, 0, (size_t)(90112 + 8192), stream);

    knrm_wpack<<<dim3(56), dim3(256), 0, stream>>>(Wt, We, bt, be, Wp, bias);
    knrm_qtrans<<<dim3((B_ * QLEN) / 8), dim3(256), 0, stream>>>(
        qtok, qent, emb, Wt, bt, We, be, qhatb);
    knrm_fused<<<dim3(DLEN / BM, B_), dim3(512), 0, stream>>>(
        dtok, dent, emb, Wp, bias, qhatb, ksum, simsum);
    knrm_final<<<dim3(B_), dim3(384), 0, stream>>>(ksum, simsum, Wc, bc, out);
}